// Round 4
// baseline (899.354 us; speedup 1.0000x reference)
//
#include <hip/hip_runtime.h>
#include <hip/hip_bf16.h>
#include <cstdint>

#define DMODEL 768
#define NB 64        // batch
#define NHEAD 12
#define DHEAD 64
#define SEQLEN 512
#define NDOM 3
#define NBLK 2
#define FFNH 3072
#define NBROWS (NDOM*NB)   // 192
#define NCH 8              // 64-row chunks per (n,b)
#define ROWCH 64

__device__ __forceinline__ float wsum64(float v){
  #pragma unroll
  for (int o = 32; o; o >>= 1) v += __shfl_xor(v, o, 64);
  return v;
}
__device__ __forceinline__ float wmax64(float v){
  #pragma unroll
  for (int o = 32; o; o >>= 1) v = fmaxf(v, __shfl_xor(v, o, 64));
  return v;
}
__device__ __forceinline__ float dot4f(float4 a, float4 b){
  return fmaf(a.x, b.x, fmaf(a.y, b.y, fmaf(a.z, b.z, a.w * b.w)));
}

// -------- LayerNorm: one wave per row of [rows, 768] --------
__global__ __launch_bounds__(256) void k_ln(const float* __restrict__ in,
    const float* __restrict__ w, const float* __restrict__ b,
    float* __restrict__ out, int rows){
  int gw = (blockIdx.x * 256 + threadIdx.x) >> 6;
  int lane = threadIdx.x & 63;
  if (gw >= rows) return;
  const float4* x4 = (const float4*)(in + (size_t)gw * DMODEL);
  float4 v0 = x4[lane], v1 = x4[64 + lane], v2 = x4[128 + lane];
  float s = v0.x+v0.y+v0.z+v0.w + v1.x+v1.y+v1.z+v1.w + v2.x+v2.y+v2.z+v2.w;
  float q = dot4f(v0,v0) + dot4f(v1,v1) + dot4f(v2,v2);
  s = wsum64(s); q = wsum64(q);
  float m = s * (1.0f / DMODEL);
  float var = q * (1.0f / DMODEL) - m * m;
  float r = rsqrtf(var + 1e-5f);
  const float4* w4 = (const float4*)w;
  const float4* b4 = (const float4*)b;
  float4* o4 = (float4*)(out + (size_t)gw * DMODEL);
  float4 vv[3] = {v0, v1, v2};
  #pragma unroll
  for (int seg = 0; seg < 3; ++seg){
    float4 ww = w4[seg*64 + lane], bb = b4[seg*64 + lane], x = vv[seg], o;
    o.x = (x.x - m) * r * ww.x + bb.x;
    o.y = (x.y - m) * r * ww.y + bb.y;
    o.z = (x.z - m) * r * ww.z + bb.z;
    o.w = (x.w - m) * r * ww.w + bb.w;
    o4[seg*64 + lane] = o;
  }
}

// -------- double LayerNorm (out_norm then cls_ln), one wave per row --------
__global__ __launch_bounds__(256) void k_ln2(const float* __restrict__ in,
    const float* __restrict__ w1, const float* __restrict__ b1,
    const float* __restrict__ w2, const float* __restrict__ b2,
    float* __restrict__ out, int rows){
  int gw = (blockIdx.x * 256 + threadIdx.x) >> 6;
  int lane = threadIdx.x & 63;
  if (gw >= rows) return;
  const float4* x4 = (const float4*)(in + (size_t)gw * DMODEL);
  float4 vv[3] = {x4[lane], x4[64 + lane], x4[128 + lane]};
  float s = 0, q = 0;
  #pragma unroll
  for (int g = 0; g < 3; ++g){
    s += vv[g].x+vv[g].y+vv[g].z+vv[g].w;
    q += dot4f(vv[g], vv[g]);
  }
  s = wsum64(s); q = wsum64(q);
  float m = s * (1.0f/DMODEL);
  float r = rsqrtf(q * (1.0f/DMODEL) - m*m + 1e-5f);
  const float4* w14 = (const float4*)w1; const float4* b14 = (const float4*)b1;
  float4 yy[3];
  float s2 = 0, q2 = 0;
  #pragma unroll
  for (int g = 0; g < 3; ++g){
    float4 ww = w14[g*64 + lane], bb = b14[g*64 + lane], x = vv[g], o;
    o.x = (x.x - m)*r*ww.x + bb.x; o.y = (x.y - m)*r*ww.y + bb.y;
    o.z = (x.z - m)*r*ww.z + bb.z; o.w = (x.w - m)*r*ww.w + bb.w;
    yy[g] = o;
    s2 += o.x+o.y+o.z+o.w; q2 += dot4f(o,o);
  }
  s2 = wsum64(s2); q2 = wsum64(q2);
  float m2 = s2 * (1.0f/DMODEL);
  float r2 = rsqrtf(q2 * (1.0f/DMODEL) - m2*m2 + 1e-5f);
  const float4* w24 = (const float4*)w2; const float4* b24 = (const float4*)b2;
  float4* o4 = (float4*)(out + (size_t)gw * DMODEL);
  #pragma unroll
  for (int g = 0; g < 3; ++g){
    float4 ww = w24[g*64 + lane], bb = b24[g*64 + lane], y = yy[g], o;
    o.x = (y.x - m2)*r2*ww.x + bb.x; o.y = (y.y - m2)*r2*ww.y + bb.y;
    o.z = (y.z - m2)*r2*ww.z + bb.z; o.w = (y.w - m2)*r2*ww.w + bb.w;
    o4[g*64 + lane] = o;
  }
}

// -------- wave-per-4-columns GEMM: out[64,NC] = act(A[64,K] @ W[NC,K]^T + bias) --------
template<int K, int NC, int ACT, bool RES>
__global__ __launch_bounds__(256) void k_gemmW(const float* __restrict__ A,
    const float* __restrict__ W, const float* __restrict__ bias,
    const float* __restrict__ res, float* __restrict__ out){
  const int NJ = NC / 4;
  int gw = (blockIdx.x * 256 + threadIdx.x) >> 6;   // 8*NJ waves
  int lane = threadIdx.x & 63;
  int sl = lane & 7, g = lane >> 3;
  int bg = gw / NJ; int j0 = (gw - bg * NJ) * 4;
  const float4* a4 = (const float4*)(A + (size_t)(bg*8 + g) * K);
  const float4* w0 = (const float4*)(W + (size_t)(j0+0) * K);
  const float4* w1 = (const float4*)(W + (size_t)(j0+1) * K);
  const float4* w2 = (const float4*)(W + (size_t)(j0+2) * K);
  const float4* w3 = (const float4*)(W + (size_t)(j0+3) * K);
  float acc0 = 0, acc1 = 0, acc2 = 0, acc3 = 0;
  #pragma unroll 4
  for (int i = 0; i < K/32; ++i){
    float4 av = a4[i*8 + sl];
    acc0 += dot4f(av, w0[i*8 + sl]);
    acc1 += dot4f(av, w1[i*8 + sl]);
    acc2 += dot4f(av, w2[i*8 + sl]);
    acc3 += dot4f(av, w3[i*8 + sl]);
  }
  #pragma unroll
  for (int o = 1; o <= 4; o <<= 1){
    acc0 += __shfl_xor(acc0, o, 64);
    acc1 += __shfl_xor(acc1, o, 64);
    acc2 += __shfl_xor(acc2, o, 64);
    acc3 += __shfl_xor(acc3, o, 64);
  }
  if (sl == 0){
    int row = bg*8 + g;
    float4 bj = *(const float4*)(bias + j0);
    float a[4] = {acc0, acc1, acc2, acc3};
    float bb[4] = {bj.x, bj.y, bj.z, bj.w};
    float v[4];
    #pragma unroll
    for (int u = 0; u < 4; ++u){
      float t = (ACT == 2) ? a[u] * (1.0f/3.0f) + bb[u] : a[u] + bb[u];
      if (ACT == 1) t = t / (1.0f + __expf(-t));
      v[u] = t;
    }
    size_t o = (size_t)row * NC + j0;
    if (RES){
      float4 rr = *(const float4*)(res + o);
      v[0] += rr.x; v[1] += rr.y; v[2] += rr.z; v[3] += rr.w;
    }
    *(float4*)(out + o) = make_float4(v[0], v[1], v[2], v[3]);
  }
}

// -------- fused qproj + reductions: wave per (b,h) --------
__global__ __launch_bounds__(256) void k_qpr(const float* __restrict__ qh,
    const float* __restrict__ Wk, const float* __restrict__ snw,
    const float* __restrict__ snb, const float* __restrict__ bk,
    float* __restrict__ QW, float* __restrict__ SQW, float* __restrict__ SC){
  int w = (blockIdx.x * 256 + threadIdx.x) >> 6;   // 768 waves
  int lane = threadIdx.x & 63;
  int b = w / NHEAD, h = w - b * NHEAD;
  const float* qrow = qh + (size_t)b * DMODEL + h * DHEAD;
  const float* wbase = Wk + (size_t)h * DHEAD * DMODEL;
  float qp[12] = {};
  for (int e = 0; e < DHEAD; ++e){
    float qv = qrow[e];
    const float* wr = wbase + (size_t)e * DMODEL;
    #pragma unroll
    for (int k = 0; k < 12; ++k) qp[k] = fmaf(qv, wr[k*64 + lane], qp[k]);
  }
  float s1 = 0, s2 = 0;
  float* qwout = QW + (size_t)w * DMODEL;
  #pragma unroll
  for (int k = 0; k < 12; ++k){
    int d = k*64 + lane;
    float q = qp[k];
    float qwv = q * snw[d] * 0.125f;
    qwout[d] = qwv;
    s1 += qwv;
    s2 = fmaf(q, snb[d], s2);
  }
  float s3 = qrow[lane] * bk[h*DHEAD + lane];
  s1 = wsum64(s1); s2 = wsum64(s2); s3 = wsum64(s3);
  if (lane == 0){ SQW[w] = s1; SC[w] = 0.125f * (s2 + s3); }
}

// -------- fused attention, LDS-tiled, transposed lane assignment --------
// block = (nb, ch): 64 rows. Phase 1: lane=row, wave=32-col slice, all 12 heads.
// Phase 2: wave=16 rows, lane=2 cols, all 12 heads. XOR-swizzled x tile.
__global__ __launch_bounds__(256) void k_attn2(const float* __restrict__ seq,
    const int* __restrict__ lens, const float* __restrict__ QW,
    const float* __restrict__ SQW, const float* __restrict__ SC,
    float* __restrict__ Pacc, float* __restrict__ Pden,
    float* __restrict__ Pc, float* __restrict__ Pmx){
  __shared__ float xt[64*128];     // 32 KB, float4-XOR-swizzled: c4phys = c4 ^ (row&7)
  __shared__ float uni[6144];      // 24 KB: phase1 = qt[12][128] + red1[4][14][64]; phase2 = red2[4][12][128]
  __shared__ float er_s[64][12];   // 3 KB
  int blk = blockIdx.x;
  int ch = blk & (NCH-1); int nb = blk >> 3;
  int len = lens[nb];
  int row0 = ch * ROWCH;
  if (row0 >= len) return;
  int b = nb % NB;
  int tid = threadIdx.x;
  int wid = tid >> 6, lane = tid & 63;
  int lr = tid >> 2;               // loader row 0..63
  int lc4 = (tid & 3) * 8;         // loader first float4-col of 32-col segment
  const float* gsrc = seq + ((size_t)nb * SEQLEN + row0 + lr) * DMODEL + lc4 * 4;
  const float* qwb = QW + (size_t)b * NHEAD * DMODEL;
  float* qt = uni;                 // [12][128]
  float* red1 = uni + 1536;        // [4][14][64]

  float dt[12];
  #pragma unroll
  for (int h = 0; h < 12; ++h) dt[h] = 0.0f;
  float sm = 0.0f, qq = 0.0f;

  // ---- phase 1: scores ----
  for (int c = 0; c < 6; ++c){
    __syncthreads();
    const float4* g4 = (const float4*)(gsrc + c*128);
    #pragma unroll
    for (int k = 0; k < 8; ++k){
      float4 v = g4[k];
      int c4p = (lc4 + k) ^ (lr & 7);
      *(float4*)&xt[lr*128 + c4p*4] = v;
    }
    #pragma unroll
    for (int i = 0; i < 6; ++i){
      int idx = tid + i*256;       // 0..1535
      qt[idx] = qwb[(size_t)(idx >> 7) * DMODEL + c*128 + (idx & 127)];
    }
    __syncthreads();
    const float4* q4 = (const float4*)qt;
    #pragma unroll
    for (int i = 0; i < 8; ++i){
      int c4 = wid*8 + i;
      int c4p = c4 ^ (lane & 7);
      float4 x = *(const float4*)&xt[lane*128 + c4p*4];
      sm += x.x + x.y + x.z + x.w;
      qq += dot4f(x, x);
      #pragma unroll
      for (int h = 0; h < 12; ++h)
        dt[h] += dot4f(q4[h*32 + c4], x);
    }
  }
  #pragma unroll
  for (int h = 0; h < 12; ++h) red1[(wid*14 + h)*64 + lane] = dt[h];
  red1[(wid*14 + 12)*64 + lane] = sm;
  red1[(wid*14 + 13)*64 + lane] = qq;
  __syncthreads();

  // ---- epilogue: wave handles heads h0..h0+2, lane = row ----
  int h0 = wid * 3;
  float smt = 0, qqt = 0, d0 = 0, d1 = 0, d2 = 0;
  #pragma unroll
  for (int w = 0; w < 4; ++w){
    smt += red1[(w*14 + 12)*64 + lane];
    qqt += red1[(w*14 + 13)*64 + lane];
    d0  += red1[(w*14 + h0    )*64 + lane];
    d1  += red1[(w*14 + h0 + 1)*64 + lane];
    d2  += red1[(w*14 + h0 + 2)*64 + lane];
  }
  float m = smt * (1.0f/DMODEL);
  float rs = rsqrtf(qqt * (1.0f/DMODEL) - m*m + 1e-5f);
  bool valid = (row0 + lane) < len;
  int bh = b*NHEAD + h0;
  float sv0 = rs*(d0 - m*SQW[bh  ]) + SC[bh  ];
  float sv1 = rs*(d1 - m*SQW[bh+1]) + SC[bh+1];
  float sv2 = rs*(d2 - m*SQW[bh+2]) + SC[bh+2];
  if (!valid){ sv0 = -3.0e38f; sv1 = -3.0e38f; sv2 = -3.0e38f; }
  float mx0 = wmax64(sv0), mx1 = wmax64(sv1), mx2 = wmax64(sv2);
  float e0 = valid ? __expf(sv0 - mx0) : 0.0f;
  float e1 = valid ? __expf(sv1 - mx1) : 0.0f;
  float e2 = valid ? __expf(sv2 - mx2) : 0.0f;
  float er0 = e0*rs, er1 = e1*rs, er2 = e2*rs;
  er_s[lane][h0] = er0; er_s[lane][h0+1] = er1; er_s[lane][h0+2] = er2;
  float den0 = wsum64(e0), den1 = wsum64(e1), den2 = wsum64(e2);
  float cc0 = wsum64(er0*m), cc1 = wsum64(er1*m), cc2 = wsum64(er2*m);
  size_t pb = (size_t)blk * NHEAD;
  if (lane == 0){
    Pden[pb+h0] = den0; Pden[pb+h0+1] = den1; Pden[pb+h0+2] = den2;
    Pc [pb+h0] = cc0;  Pc [pb+h0+1] = cc1;  Pc [pb+h0+2] = cc2;
    Pmx[pb+h0] = mx0;  Pmx[pb+h0+1] = mx1;  Pmx[pb+h0+2] = mx2;
  }

  // ---- phase 2: weighted accumulation, wave = rows [wid*16, +16), lane = cols (2*lane, 2*lane+1) ----
  float* red2 = uni;               // [4][12][128]
  int prow0 = wid * 16;
  for (int c = 0; c < 6; ++c){
    __syncthreads();
    const float4* g4 = (const float4*)(gsrc + c*128);
    #pragma unroll
    for (int k = 0; k < 8; ++k){
      float4 v = g4[k];
      int c4p = (lc4 + k) ^ (lr & 7);
      *(float4*)&xt[lr*128 + c4p*4] = v;
    }
    __syncthreads();
    float pa[12][2];
    #pragma unroll
    for (int h = 0; h < 12; ++h){ pa[h][0] = 0.0f; pa[h][1] = 0.0f; }
    #pragma unroll
    for (int si = 0; si < 16; ++si){
      int s = prow0 + si;
      int c4p = (lane >> 1) ^ (s & 7);
      float2 xv = *(const float2*)&xt[s*128 + c4p*4 + (lane & 1)*2];
      float4 ea = *(const float4*)&er_s[s][0];
      float4 eb = *(const float4*)&er_s[s][4];
      float4 ec = *(const float4*)&er_s[s][8];
      pa[0][0]  = fmaf(ea.x, xv.x, pa[0][0]);  pa[0][1]  = fmaf(ea.x, xv.y, pa[0][1]);
      pa[1][0]  = fmaf(ea.y, xv.x, pa[1][0]);  pa[1][1]  = fmaf(ea.y, xv.y, pa[1][1]);
      pa[2][0]  = fmaf(ea.z, xv.x, pa[2][0]);  pa[2][1]  = fmaf(ea.z, xv.y, pa[2][1]);
      pa[3][0]  = fmaf(ea.w, xv.x, pa[3][0]);  pa[3][1]  = fmaf(ea.w, xv.y, pa[3][1]);
      pa[4][0]  = fmaf(eb.x, xv.x, pa[4][0]);  pa[4][1]  = fmaf(eb.x, xv.y, pa[4][1]);
      pa[5][0]  = fmaf(eb.y, xv.x, pa[5][0]);  pa[5][1]  = fmaf(eb.y, xv.y, pa[5][1]);
      pa[6][0]  = fmaf(eb.z, xv.x, pa[6][0]);  pa[6][1]  = fmaf(eb.z, xv.y, pa[6][1]);
      pa[7][0]  = fmaf(eb.w, xv.x, pa[7][0]);  pa[7][1]  = fmaf(eb.w, xv.y, pa[7][1]);
      pa[8][0]  = fmaf(ec.x, xv.x, pa[8][0]);  pa[8][1]  = fmaf(ec.x, xv.y, pa[8][1]);
      pa[9][0]  = fmaf(ec.y, xv.x, pa[9][0]);  pa[9][1]  = fmaf(ec.y, xv.y, pa[9][1]);
      pa[10][0] = fmaf(ec.z, xv.x, pa[10][0]); pa[10][1] = fmaf(ec.z, xv.y, pa[10][1]);
      pa[11][0] = fmaf(ec.w, xv.x, pa[11][0]); pa[11][1] = fmaf(ec.w, xv.y, pa[11][1]);
    }
    #pragma unroll
    for (int h = 0; h < 12; ++h)
      *(float2*)&red2[(wid*12 + h)*128 + 2*lane] = make_float2(pa[h][0], pa[h][1]);
    __syncthreads();
    size_t pacc_base = (size_t)blk * NHEAD * DMODEL + c*128;
    #pragma unroll
    for (int i = 0; i < 6; ++i){
      int idx = tid + i*256;       // 0..1535
      int h = idx >> 7, d = idx & 127;
      float v = red2[h*128 + d] + red2[(12 + h)*128 + d]
              + red2[(24 + h)*128 + d] + red2[(36 + h)*128 + d];
      Pacc[pacc_base + (size_t)h * DMODEL + d] = v;
    }
  }
}

// -------- combine active chunk partials over ch and domains + seq-LN affine --------
__global__ __launch_bounds__(256) void k_comb(const float* __restrict__ Pacc,
    const float* __restrict__ Pden, const float* __restrict__ Pc,
    const float* __restrict__ Pmx, const int* __restrict__ lens,
    const float* __restrict__ snw, const float* __restrict__ snb,
    float* __restrict__ wsum){
  int tid = blockIdx.x * 256 + threadIdx.x;   // NB*NHEAD*DMODEL
  int d = tid % DMODEL;
  int t = tid / DMODEL;
  int h = t % NHEAD;
  int b = t / NHEAD;
  float vec = 0.0f, csum = 0.0f;
  #pragma unroll
  for (int n = 0; n < NDOM; ++n){
    int nb = n*NB + b;
    int len = lens[nb];
    int na = (len + ROWCH - 1) >> 6; if (na > NCH) na = NCH;
    size_t p0 = (size_t)nb * NCH * NHEAD + h;
    float M = -3.0e38f;
    for (int c = 0; c < na; ++c) M = fmaxf(M, Pmx[p0 + (size_t)c*NHEAD]);
    float D = 0, V = 0, C = 0;
    for (int c = 0; c < na; ++c){
      size_t pi = p0 + (size_t)c*NHEAD;
      float w = __expf(Pmx[pi] - M);
      D = fmaf(w, Pden[pi], D);
      V = fmaf(w, Pacc[pi*DMODEL + d], V);
      C = fmaf(w, Pc[pi], C);
    }
    float inv = 1.0f / D;
    vec = fmaf(V, inv, vec);
    csum = fmaf(C, inv, csum);
  }
  wsum[tid] = (vec - csum) * snw[d] + 3.0f * snb[d];
}

// -------- ctxsum[b,he] = sum_d wsum[b,h,d]*Wv[he,d] + 3*bv[he], wave per 4 he --------
__global__ __launch_bounds__(256) void k_ctxv2(const float* __restrict__ wsum,
    const float* __restrict__ Wv, const float* __restrict__ bv, float* __restrict__ ctxsum){
  int gw = (blockIdx.x * 256 + threadIdx.x) >> 6;   // 8*192 waves
  int lane = threadIdx.x & 63;
  int sl = lane & 7, g = lane >> 3;
  int bg = gw / 192; int j0 = (gw - bg * 192) * 4;
  int h = j0 >> 6;
  const float4* a4 = (const float4*)(wsum + ((size_t)(bg*8 + g) * NHEAD + h) * DMODEL);
  const float4* w0 = (const float4*)(Wv + (size_t)(j0+0) * DMODEL);
  const float4* w1 = (const float4*)(Wv + (size_t)(j0+1) * DMODEL);
  const float4* w2 = (const float4*)(Wv + (size_t)(j0+2) * DMODEL);
  const float4* w3 = (const float4*)(Wv + (size_t)(j0+3) * DMODEL);
  float acc0 = 0, acc1 = 0, acc2 = 0, acc3 = 0;
  #pragma unroll 4
  for (int i = 0; i < DMODEL/32; ++i){
    float4 av = a4[i*8 + sl];
    acc0 += dot4f(av, w0[i*8 + sl]);
    acc1 += dot4f(av, w1[i*8 + sl]);
    acc2 += dot4f(av, w2[i*8 + sl]);
    acc3 += dot4f(av, w3[i*8 + sl]);
  }
  #pragma unroll
  for (int o = 1; o <= 4; o <<= 1){
    acc0 += __shfl_xor(acc0, o, 64);
    acc1 += __shfl_xor(acc1, o, 64);
    acc2 += __shfl_xor(acc2, o, 64);
    acc3 += __shfl_xor(acc3, o, 64);
  }
  if (sl == 0){
    float4 bb = *(const float4*)(bv + j0);
    float4 v = make_float4(acc0 + 3.0f*bb.x, acc1 + 3.0f*bb.y, acc2 + 3.0f*bb.z, acc3 + 3.0f*bb.w);
    *(float4*)(ctxsum + (size_t)(bg*8 + g) * DMODEL + j0) = v;
  }
}

// -------- gate + residual, wave per 4 cols --------
__global__ __launch_bounds__(256) void k_gate2(const float* __restrict__ ctx,
    const float* __restrict__ sctx, const float* __restrict__ Wg,
    const float* __restrict__ gb, float* __restrict__ out){
  int gw = (blockIdx.x * 256 + threadIdx.x) >> 6;   // 8*192 waves
  int lane = threadIdx.x & 63;
  int sl = lane & 7, g = lane >> 3;
  int bg = gw / 192; int j0 = (gw - bg * 192) * 4;
  int row = bg*8 + g;
  const float4* c4 = (const float4*)(ctx + (size_t)row * DMODEL);
  const float4* s4 = (const float4*)(sctx + (size_t)row * DMODEL);
  const float4* wr0 = (const float4*)(Wg + (size_t)(j0+0) * 2 * DMODEL);
  const float4* wr1 = (const float4*)(Wg + (size_t)(j0+1) * 2 * DMODEL);
  const float4* wr2 = (const float4*)(Wg + (size_t)(j0+2) * 2 * DMODEL);
  const float4* wr3 = (const float4*)(Wg + (size_t)(j0+3) * 2 * DMODEL);
  float acc0 = 0, acc1 = 0, acc2 = 0, acc3 = 0;
  #pragma unroll 4
  for (int i = 0; i < DMODEL/32; ++i){
    float4 cv = c4[i*8 + sl], sv = s4[i*8 + sl];
    acc0 += dot4f(cv, wr0[i*8 + sl]) + dot4f(sv, wr0[192 + i*8 + sl]);
    acc1 += dot4f(cv, wr1[i*8 + sl]) + dot4f(sv, wr1[192 + i*8 + sl]);
    acc2 += dot4f(cv, wr2[i*8 + sl]) + dot4f(sv, wr2[192 + i*8 + sl]);
    acc3 += dot4f(cv, wr3[i*8 + sl]) + dot4f(sv, wr3[192 + i*8 + sl]);
  }
  #pragma unroll
  for (int o = 1; o <= 4; o <<= 1){
    acc0 += __shfl_xor(acc0, o, 64);
    acc1 += __shfl_xor(acc1, o, 64);
    acc2 += __shfl_xor(acc2, o, 64);
    acc3 += __shfl_xor(acc3, o, 64);
  }
  if (sl == 0){
    size_t o = (size_t)row * DMODEL + j0;
    float4 bb = *(const float4*)(gb + j0);
    float4 cc = *(const float4*)(ctx + o);
    float4 ss = *(const float4*)(sctx + o);
    float4 v;
    v.x = cc.x + ss.x / (1.0f + __expf(-(acc0 + bb.x)));
    v.y = cc.y + ss.y / (1.0f + __expf(-(acc1 + bb.y)));
    v.z = cc.z + ss.z / (1.0f + __expf(-(acc2 + bb.z)));
    v.w = cc.w + ss.w / (1.0f + __expf(-(acc3 + bb.w)));
    *(float4*)(out + o) = v;
  }
}

// -------- classifier final dot --------
__global__ __launch_bounds__(256) void k_cls2(const float* __restrict__ h2,
    const float* __restrict__ w2, const float* __restrict__ b2, float* __restrict__ out){
  int b = blockIdx.x; int t = threadIdx.x;
  float acc = 0;
  for (int j = t; j < FFNH; j += 256) acc = fmaf(h2[(size_t)b*FFNH + j], w2[j], acc);
  acc = wsum64(acc);
  __shared__ float sh[4];
  if ((t & 63) == 0) sh[t >> 6] = acc;
  __syncthreads();
  if (t == 0) out[b] = sh[0] + sh[1] + sh[2] + sh[3] + b2[0];
}

extern "C" void kernel_launch(void* const* d_in, const int* in_sizes, int n_in,
                              void* d_out, int out_size, void* d_ws, size_t ws_size,
                              hipStream_t stream){
  const float* in_ctx = (const float*)d_in[0];
  const float* seq    = (const float*)d_in[1];
  const int*   lens   = (const int*)d_in[2];
  const float* qn_w   = (const float*)d_in[3];
  const float* qn_b   = (const float*)d_in[4];
  const float* sn_w   = (const float*)d_in[5];
  const float* sn_b   = (const float*)d_in[6];
  const float* in_w   = (const float*)d_in[7];
  const float* in_b   = (const float*)d_in[8];
  const float* out_w  = (const float*)d_in[9];
  const float* out_b  = (const float*)d_in[10];
  const float* gate_w = (const float*)d_in[11];
  const float* gate_b = (const float*)d_in[12];
  const float* fln_w  = (const float*)d_in[13];
  const float* fln_b  = (const float*)d_in[14];
  const float* fw1    = (const float*)d_in[15];
  const float* fb1    = (const float*)d_in[16];
  const float* fw2    = (const float*)d_in[17];
  const float* fb2    = (const float*)d_in[18];
  const float* on_w   = (const float*)d_in[19];
  const float* on_b   = (const float*)d_in[20];
  const float* cl_w   = (const float*)d_in[21];
  const float* cl_b   = (const float*)d_in[22];
  const float* cw1    = (const float*)d_in[23];
  const float* cb1    = (const float*)d_in[24];
  const float* cw2    = (const float*)d_in[25];
  const float* cb2    = (const float*)d_in[26];

  float* wsf = (float*)d_ws;
  size_t off = 0;
  auto alloc = [&](size_t n){ float* p = wsf + off; off += n; return p; };
  float* c0     = alloc((size_t)NB*DMODEL);
  float* c1     = alloc((size_t)NB*DMODEL);
  float* cmid   = alloc((size_t)NB*DMODEL);
  float* qln    = alloc((size_t)NB*DMODEL);
  float* qh     = alloc((size_t)NB*DMODEL);
  float* QW     = alloc((size_t)NB*NHEAD*DMODEL);
  float* SQWb   = alloc((size_t)NB*NHEAD);
  float* SCb    = alloc((size_t)NB*NHEAD);
  float* Pacc   = alloc((size_t)NBROWS*NCH*NHEAD*DMODEL);
  float* Pden   = alloc((size_t)NBROWS*NCH*NHEAD);
  float* Pc     = alloc((size_t)NBROWS*NCH*NHEAD);
  float* Pmx    = alloc((size_t)NBROWS*NCH*NHEAD);
  float* wsumb  = alloc((size_t)NB*NHEAD*DMODEL);
  float* ctxsum = alloc((size_t)NB*DMODEL);
  float* sctx   = alloc((size_t)NB*DMODEL);
  float* h0     = alloc((size_t)NB*DMODEL);
  float* h1     = alloc((size_t)NB*FFNH);
  (void)ws_size; (void)in_sizes; (void)n_in; (void)out_size;

  hipMemcpyAsync(c0, in_ctx, (size_t)NB*DMODEL*sizeof(float), hipMemcpyDeviceToDevice, stream);
  float* cur = c0; float* nxt = c1;

  for (int l = 0; l < NBLK; ++l){
    const float* Wq = in_w + (size_t)l * 3 * DMODEL * DMODEL;
    const float* Wk = Wq + (size_t)DMODEL * DMODEL;
    const float* Wv = Wq + (size_t)2 * DMODEL * DMODEL;
    const float* bq = in_b + (size_t)l * 3 * DMODEL;
    const float* bk = bq + DMODEL;
    const float* bv = bq + 2 * DMODEL;

    k_ln<<<16, 256, 0, stream>>>(cur, qn_w + l*DMODEL, qn_b + l*DMODEL, qln, NB);
    k_gemmW<DMODEL,DMODEL,0,false><<<384, 256, 0, stream>>>(qln, Wq, bq, nullptr, qh);
    k_qpr<<<192, 256, 0, stream>>>(qh, Wk, sn_w + l*DMODEL, sn_b + l*DMODEL, bk, QW, SQWb, SCb);
    k_attn2<<<NBROWS*NCH, 256, 0, stream>>>(seq, lens, QW, SQWb, SCb, Pacc, Pden, Pc, Pmx);
    k_comb<<<(NB*NHEAD*DMODEL)/256, 256, 0, stream>>>(Pacc, Pden, Pc, Pmx, lens, sn_w + l*DMODEL, sn_b + l*DMODEL, wsumb);
    k_ctxv2<<<384, 256, 0, stream>>>(wsumb, Wv, bv, ctxsum);
    k_gemmW<DMODEL,DMODEL,2,false><<<384, 256, 0, stream>>>(ctxsum, out_w + (size_t)l*DMODEL*DMODEL, out_b + l*DMODEL, nullptr, sctx);
    k_gate2<<<384, 256, 0, stream>>>(cur, sctx, gate_w + (size_t)l*DMODEL*2*DMODEL, gate_b + l*DMODEL, cmid);
    k_ln<<<16, 256, 0, stream>>>(cmid, fln_w + l*DMODEL, fln_b + l*DMODEL, h0, NB);
    k_gemmW<DMODEL,FFNH,1,false><<<1536, 256, 0, stream>>>(h0, fw1 + (size_t)l*FFNH*DMODEL, fb1 + l*FFNH, nullptr, h1);
    k_gemmW<FFNH,DMODEL,0,true><<<384, 256, 0, stream>>>(h1, fw2 + (size_t)l*DMODEL*FFNH, fb2 + l*DMODEL, cmid, nxt);
    float* t = cur; cur = nxt; nxt = t;
  }

  k_ln2<<<16, 256, 0, stream>>>(cur, on_w, on_b, cl_w, cl_b, h0, NB);
  k_gemmW<DMODEL,FFNH,1,false><<<1536, 256, 0, stream>>>(h0, cw1, cb1, nullptr, h1);
  k_cls2<<<64, 256, 0, stream>>>(h1, cw2, cb2, (float*)d_out);
}